// Round 7
// baseline (98.011 us; speedup 1.0000x reference)
//
#include <hip/hip_runtime.h>
#include <math.h>

#define B_ 3
#define P_ 768
#define F_ 1024
#define H_ 128
#define W_ 128
#define HW_ (H_*W_)
#define EPS_ 1e-8f

// Output layout (flat concat, floats):
//   imrender (1,128,128,3) : offset 0,      49152
//   improb   (128,128,1)   : offset 49152,  16384
//   normals  (3,1024,3)    : offset 65536,   9216
//   fg       (1,128,128,1) : offset 74752,  16384
#define OFF_PROB   49152
#define OFF_NORM   65536
#define OFF_FG     74752

// Workspace layout (bytes):
//   faceA:  B*F float4  (e0x,e0y,e1x,e1y)        @ 0       (49152 B)
//   faceB:  B*F float4  (cx,cy,denom,valid)      @ 49152
//   packed: B*HW u64    ((z_bits<<32)|faceidx)   @ 98304   (393216 B)
// NOTE: harness poisons the FULL d_ws (256 MiB) to 0xAA every timed iter —
// that fill is ~43 us of the measured time and is not controllable here.

// Forward rasterizer: ONE WAVE PER FACE. The wave computes its face's setup
// in-register, lane 0 writes normals + per-face shading data, then lanes
// stripe the face's conservative pixel bbox and atomicMin a packed
// (z_bits<<32)|idx u64 per covered pixel. Positive-float bits are
// value-monotone, so u64-min == (min z, then min idx) == jnp.argmin
// first-occurrence tie-break — order-independent across waves.
__global__ __launch_bounds__(256) void raster_fwd(
    const float* __restrict__ points,
    const float* __restrict__ camrot,
    const float* __restrict__ campos,
    const float* __restrict__ proj,
    const int*   __restrict__ faces,
    float4* __restrict__ faceA,
    float4* __restrict__ faceB,
    unsigned long long* __restrict__ packed,
    float*  __restrict__ normals_out)
{
#pragma clang fp contract(off)
    int wid  = blockIdx.x * 4 + (threadIdx.x >> 6);   // global wave = face slot
    int lane = threadIdx.x & 63;
    int b = wid / F_;
    int f = wid - b * F_;

    // ---- per-face setup (bit-identical expressions to the validated r3/r4
    //      setup_faces, compiled under contract(off)) ----
    const float* R = camrot + b * 9;
    float cpx = campos[b*3+0], cpy = campos[b*3+1], cpz = campos[b*3+2];
    float pj0 = proj[0], pj1 = proj[1];

    float pcx[3], pcy[3], pcz[3], sx[3], sy[3];
    for (int v = 0; v < 3; ++v) {
        int vi = faces[f*3 + v];
        const float* P = points + (b*P_ + vi) * 3;
        float vx = P[0] - cpx;
        float vy = P[1] - cpy;
        float vz = P[2] - cpz;
        float qx = (vx*R[0] + vy*R[1]) + vz*R[2];
        float qy = (vx*R[3] + vy*R[4]) + vz*R[5];
        float qz = (vx*R[6] + vy*R[7]) + vz*R[8];
        pcx[v] = qx; pcy[v] = qy; pcz[v] = qz;
        float dz = qz + EPS_;
        sx[v] = (qx * pj0) / dz;
        sy[v] = (qy * pj1) / dz;
    }

    float ax = sx[0], ay = sy[0];
    float bx = sx[1], by = sy[1];
    float cx = sx[2], cy = sy[2];

    float e0x = by - cy;
    float e0y = cx - bx;
    float e1x = cy - ay;
    float e1y = ax - cx;
    float d = e0x*(ax - cx) + e0y*(ay - cy);
    float denom = d + EPS_;
    bool valid = fabsf(d) > EPS_;
    float z0 = pcz[0], z1 = pcz[1], z2 = pcz[2];

    if (lane == 0) {
        faceA[wid] = make_float4(e0x, e0y, e1x, e1y);
        faceB[wid] = make_float4(cx, cy, denom, valid ? 1.0f : 0.0f);

        // normal: emulate XLA's LHS-fma contraction (validated bitwise, r3).
        float ux = pcx[1]-pcx[0], uy = pcy[1]-pcy[0], uz = pcz[1]-pcz[0];
        float wx = pcx[2]-pcx[0], wy = pcy[2]-pcy[0], wz = pcz[2]-pcz[0];
        float nx = fmaf(uy, wz, -(uz*wy));
        float ny = fmaf(uz, wx, -(ux*wz));
        float nz = fmaf(ux, wy, -(uy*wx));
        float nn = sqrtf((nx*nx + ny*ny) + nz*nz) + 1e-8f;
        normals_out[wid*3+0] = nx / nn;
        normals_out[wid*3+1] = ny / nn;
        normals_out[wid*3+2] = nz / nn;
    }

    if (!valid) return;   // inside==false for every pixel of this face

    // ---- conservative pixel-index bbox (1-px guard, validated r6) ----
    float gx0 = (ax + 1.0f) * 63.5f;
    float gx1 = (bx + 1.0f) * 63.5f;
    float gx2 = (cx + 1.0f) * 63.5f;
    float gy0 = (1.0f - ay) * 63.5f;
    float gy1 = (1.0f - by) * 63.5f;
    float gy2 = (1.0f - cy) * 63.5f;
    int xlo = max(0,   (int)ceilf (fminf(fminf(gx0,gx1),gx2) - 1.0f));
    int xhi = min(127, (int)floorf(fmaxf(fmaxf(gx0,gx1),gx2) + 1.0f));
    int ylo = max(0,   (int)ceilf (fminf(fminf(gy0,gy1),gy2) - 1.0f));
    int yhi = min(127, (int)floorf(fmaxf(fmaxf(gy0,gy1),gy2) + 1.0f));
    int wX = xhi - xlo + 1;
    int wY = yhi - ylo + 1;
    if (wX <= 0 || wY <= 0) return;
    int N = wX * wY;

    // incremental i -> (xx,yy) decomposition: one div at entry, O(1)/step
    int q64 = 64 / wX;
    int r64 = 64 - q64 * wX;
    int yy = lane / wX;
    int xx = lane - yy * wX;

    const double STEP = 2.0 / 127.0;
    unsigned long long* cells = packed + b * HW_;

    for (int i = lane; i < N; i += 64) {
        int X = xlo + xx;
        int Y = ylo + yy;
        float px = (float)(-1.0 + (double)X * STEP);
        float py = (float)( 1.0 - (double)Y * STEP);
        float dx = px - cx;
        float dy = py - cy;
        float n0 = e0x*dx + e0y*dy;
        float n1 = e1x*dx + e1y*dy;
        float l0 = n0 / denom;
        float l1 = n1 / denom;
        float l2 = 1.0f - l0 - l1;
        float zz = (l0*z0 + l1*z1) + l2*z2;
        if (l0 >= 0.0f && l1 >= 0.0f && l2 >= 0.0f && zz > EPS_) {
            unsigned long long pk =
                ((unsigned long long)__float_as_uint(zz) << 32) | (unsigned)f;
            unsigned long long* cp = &cells[Y * W_ + X];
            // Depth filter: within this dispatch cell values only decrease,
            // and any cached value is from earlier in this kernel (launch
            // acquire invalidated L1), so loaded >= current. Skipping when
            // pk >= loaded only skips atomics that would be no-ops. Safe.
            if (pk < *cp) atomicMin(cp, pk);
        }
        xx += r64; yy += q64;
        if (xx >= wX) { xx -= wX; yy += 1; }
    }
}

// Decode winner, shade (same arithmetic as the validated round-3 kernel),
// and composite all 3 batches in ts-sorted order — fused epilogue.
__global__ __launch_bounds__(256) void shade_composite(
    const float4* __restrict__ faceA,
    const float4* __restrict__ faceB,
    const int*    __restrict__ faces,
    const float*  __restrict__ uv,
    const float*  __restrict__ tex,
    const float*  __restrict__ ts,
    const unsigned long long* __restrict__ packed,
    float* __restrict__ out)
{
#pragma clang fp contract(off)
    int pix = blockIdx.x * 256 + threadIdx.x;
    int y = pix >> 7;
    int x = pix & (W_ - 1);

    const double STEP = 2.0 / 127.0;
    float px = (float)(-1.0 + (double)x * STEP);
    float py = (float)( 1.0 - (double)y * STEP);

    const unsigned MISS_BITS = __float_as_uint(1e10f);

    float rr[B_], gg[B_], bb_[B_], mm[B_];
    for (int b = 0; b < B_; ++b) {
        unsigned long long pk = packed[b * HW_ + pix];
        unsigned zbits = (unsigned)(pk >> 32);
        bool hard = zbits < MISS_BITS;
        float r = 0.0f, g = 0.0f, bl = 0.0f, m = 0.0f;
        if (hard) {
            m = 1.0f;
            int fi = (int)(unsigned)pk;   // face idx within batch
            float4 A = faceA[b * F_ + fi];
            float4 Bv = faceB[b * F_ + fi];
            float dx = px - Bv.x;
            float dy = py - Bv.y;
            float n0 = A.x*dx + A.y*dy;
            float n1 = A.z*dx + A.w*dy;
            float l0 = n0 / Bv.z;
            float l1 = n1 / Bv.z;
            float l2 = 1.0f - l0 - l1;

            int i0 = faces[fi*3+0];
            int i1 = faces[fi*3+1];
            int i2 = faces[fi*3+2];
            const float* uvb = uv + b * P_ * 2;
            float u0 = uvb[i0*2+0], v0 = uvb[i0*2+1];
            float u1 = uvb[i1*2+0], v1 = uvb[i1*2+1];
            float u2 = uvb[i2*2+0], v2 = uvb[i2*2+1];
            float tu = (l0*u0 + l1*u1) + l2*u2;
            float tv = (l0*v0 + l1*v1) + l2*v2;
            float uc = fminf(fmaxf(tu, 0.0f), 1.0f);
            float vc = fminf(fmaxf(tv, 0.0f), 1.0f);
            int txi = (int)rintf(uc * 511.0f);
            int tyi = (int)rintf((1.0f - vc) * 511.0f);
            const float* tb = tex + b * 3 * 512 * 512;
            r  = tb[(0*512 + tyi)*512 + txi];
            g  = tb[(1*512 + tyi)*512 + txi];
            bl = tb[(2*512 + tyi)*512 + txi];
        }
        rr[b] = r; gg[b] = g; bb_[b] = bl; mm[b] = m;
    }

    // stable sort descending by ts[:,2] (argsort(-ts[:,2]))
    float k0 = ts[0*3+2], k1 = ts[1*3+2], k2 = ts[2*3+2];
    int o0 = 0, o1 = 1, o2 = 2;
    if (k1 > k0) { int ti=o0; o0=o1; o1=ti; float tf=k0; k0=k1; k1=tf; }
    if (k2 > k1) { int ti=o1; o1=o2; o2=ti; float tf=k1; k1=k2; k2=tf; }
    if (k1 > k0) { int ti=o0; o0=o1; o1=ti; float tf=k0; k0=k1; k1=tf; }

    float sr = rr[o0], sg = gg[o0], sb = bb_[o0], sm = mm[o0];
    if (mm[o1] > 0.5f) { sr = rr[o1]; sg = gg[o1]; sb = bb_[o1]; sm = mm[o1]; }
    if (mm[o2] > 0.5f) { sr = rr[o2]; sg = gg[o2]; sb = bb_[o2]; sm = mm[o2]; }

    out[pix*3+0] = sr;
    out[pix*3+1] = sg;
    out[pix*3+2] = sb;
    out[OFF_PROB + pix] = sm;  // improb
    out[OFF_FG   + pix] = sm;  // fg
}

extern "C" void kernel_launch(void* const* d_in, const int* in_sizes, int n_in,
                              void* d_out, int out_size, void* d_ws, size_t ws_size,
                              hipStream_t stream) {
    const float* points = (const float*)d_in[0];
    const float* camrot = (const float*)d_in[1];
    const float* campos = (const float*)d_in[2];
    const float* proj   = (const float*)d_in[3];
    const float* uv     = (const float*)d_in[4];
    const float* tex    = (const float*)d_in[5];
    const float* ts     = (const float*)d_in[6];
    const int*   faces  = (const int*)d_in[7];
    float* out = (float*)d_out;

    char* ws = (char*)d_ws;
    float4* faceA = (float4*)(ws);
    float4* faceB = (float4*)(ws + 49152);
    unsigned long long* packed = (unsigned long long*)(ws + 98304);

    // init depth cells to u64-max (miss). Misses never write in fwd raster.
    // (Kept explicit: relying on the 0xAA poison as init would break if the
    // unprofiled correctness call ever sees non-poisoned ws.)
    hipMemsetAsync(packed, 0xFF, (size_t)B_ * HW_ * 8, stream);

    raster_fwd<<<dim3(B_*F_/4), dim3(256), 0, stream>>>(
        points, camrot, campos, proj, faces, faceA, faceB, packed,
        out + OFF_NORM);
    shade_composite<<<dim3(HW_/256), dim3(256), 0, stream>>>(
        faceA, faceB, faces, uv, tex, ts, packed, out);
}

// Round 8
// 88.821 us; speedup vs baseline: 1.1035x; 1.1035x over previous
//
#include <hip/hip_runtime.h>
#include <math.h>

#define B_ 3
#define P_ 768
#define F_ 1024
#define H_ 128
#define W_ 128
#define HW_ (H_*W_)
#define EPS_ 1e-8f

// Output layout (flat concat, floats):
//   imrender (1,128,128,3) : offset 0,      49152
//   improb   (128,128,1)   : offset 49152,  16384
//   normals  (3,1024,3)    : offset 65536,   9216
//   fg       (1,128,128,1) : offset 74752,  16384
#define OFF_PROB   49152
#define OFF_NORM   65536
#define OFF_FG     74752

// Workspace layout (bytes):
//   faceA:  B*F float4  (e0x,e0y,e1x,e1y)        @ 0       (49152 B)
//   faceB:  B*F float4  (cx,cy,denom,valid)      @ 49152
//   packed: B*HW u64    ((z_bits<<32)|faceidx)   @ 98304   (393216 B)
// NOTE: harness poisons the FULL d_ws (256 MiB) to 0xAA every timed iter —
// ~41-43 us of measured time, untouchable. Fixed floor ~64 us incl. restores.

// Forward rasterizer: ONE WAVE PER FACE (validated r6, 89.9 us). Wave computes
// face setup in-register, lane 0 writes normals + per-face shading data, lanes
// stripe the conservative pixel bbox and atomicMin packed (z_bits<<32)|idx.
// Positive-float bits are value-monotone, so u64-min == (min z, then min idx)
// == jnp.argmin first-occurrence tie-break — order-independent across waves.
// r7 LESSON: do NOT pre-load the cell to filter the atomic — result-unused
// atomicMin is fire-and-forget (no vmcnt wait); the filter load added a
// blocking dependency and cost +8 us.
__global__ __launch_bounds__(256) void raster_fwd(
    const float* __restrict__ points,
    const float* __restrict__ camrot,
    const float* __restrict__ campos,
    const float* __restrict__ proj,
    const int*   __restrict__ faces,
    float4* __restrict__ faceA,
    float4* __restrict__ faceB,
    unsigned long long* __restrict__ packed,
    float*  __restrict__ normals_out)
{
#pragma clang fp contract(off)
    int wid  = blockIdx.x * 4 + (threadIdx.x >> 6);   // global wave = face slot
    int lane = threadIdx.x & 63;
    int b = wid / F_;
    int f = wid - b * F_;

    // ---- per-face setup (bit-identical to validated r3/r4, contract(off)) ----
    const float* R = camrot + b * 9;
    float cpx = campos[b*3+0], cpy = campos[b*3+1], cpz = campos[b*3+2];
    float pj0 = proj[0], pj1 = proj[1];

    float pcx[3], pcy[3], pcz[3], sx[3], sy[3];
    for (int v = 0; v < 3; ++v) {
        int vi = faces[f*3 + v];
        const float* P = points + (b*P_ + vi) * 3;
        float vx = P[0] - cpx;
        float vy = P[1] - cpy;
        float vz = P[2] - cpz;
        float qx = (vx*R[0] + vy*R[1]) + vz*R[2];
        float qy = (vx*R[3] + vy*R[4]) + vz*R[5];
        float qz = (vx*R[6] + vy*R[7]) + vz*R[8];
        pcx[v] = qx; pcy[v] = qy; pcz[v] = qz;
        float dz = qz + EPS_;
        sx[v] = (qx * pj0) / dz;
        sy[v] = (qy * pj1) / dz;
    }

    float ax = sx[0], ay = sy[0];
    float bx = sx[1], by = sy[1];
    float cx = sx[2], cy = sy[2];

    float e0x = by - cy;
    float e0y = cx - bx;
    float e1x = cy - ay;
    float e1y = ax - cx;
    float d = e0x*(ax - cx) + e0y*(ay - cy);
    float denom = d + EPS_;
    bool valid = fabsf(d) > EPS_;
    float z0 = pcz[0], z1 = pcz[1], z2 = pcz[2];

    if (lane == 0) {
        faceA[wid] = make_float4(e0x, e0y, e1x, e1y);
        faceB[wid] = make_float4(cx, cy, denom, valid ? 1.0f : 0.0f);

        // normal: emulate XLA's LHS-fma contraction (validated bitwise, r3).
        float ux = pcx[1]-pcx[0], uy = pcy[1]-pcy[0], uz = pcz[1]-pcz[0];
        float wx = pcx[2]-pcx[0], wy = pcy[2]-pcy[0], wz = pcz[2]-pcz[0];
        float nx = fmaf(uy, wz, -(uz*wy));
        float ny = fmaf(uz, wx, -(ux*wz));
        float nz = fmaf(ux, wy, -(uy*wx));
        float nn = sqrtf((nx*nx + ny*ny) + nz*nz) + 1e-8f;
        normals_out[wid*3+0] = nx / nn;
        normals_out[wid*3+1] = ny / nn;
        normals_out[wid*3+2] = nz / nn;
    }

    if (!valid) return;   // inside==false for every pixel of this face

    // ---- conservative pixel-index bbox (1-px guard, validated r6) ----
    float gx0 = (ax + 1.0f) * 63.5f;
    float gx1 = (bx + 1.0f) * 63.5f;
    float gx2 = (cx + 1.0f) * 63.5f;
    float gy0 = (1.0f - ay) * 63.5f;
    float gy1 = (1.0f - by) * 63.5f;
    float gy2 = (1.0f - cy) * 63.5f;
    int xlo = max(0,   (int)ceilf (fminf(fminf(gx0,gx1),gx2) - 1.0f));
    int xhi = min(127, (int)floorf(fmaxf(fmaxf(gx0,gx1),gx2) + 1.0f));
    int ylo = max(0,   (int)ceilf (fminf(fminf(gy0,gy1),gy2) - 1.0f));
    int yhi = min(127, (int)floorf(fmaxf(fmaxf(gy0,gy1),gy2) + 1.0f));
    int wX = xhi - xlo + 1;
    int wY = yhi - ylo + 1;
    if (wX <= 0 || wY <= 0) return;
    int N = wX * wY;

    // incremental i -> (xx,yy) decomposition: one div at entry, O(1)/step
    int q64 = 64 / wX;
    int r64 = 64 - q64 * wX;
    int yy = lane / wX;
    int xx = lane - yy * wX;

    const double STEP = 2.0 / 127.0;
    unsigned long long* cells = packed + b * HW_;

    for (int i = lane; i < N; i += 64) {
        int X = xlo + xx;
        int Y = ylo + yy;
        float px = (float)(-1.0 + (double)X * STEP);
        float py = (float)( 1.0 - (double)Y * STEP);
        float dx = px - cx;
        float dy = py - cy;
        float n0 = e0x*dx + e0y*dy;
        float n1 = e1x*dx + e1y*dy;
        float l0 = n0 / denom;
        float l1 = n1 / denom;
        float l2 = 1.0f - l0 - l1;
        float zz = (l0*z0 + l1*z1) + l2*z2;
        if (l0 >= 0.0f && l1 >= 0.0f && l2 >= 0.0f && zz > EPS_) {
            unsigned long long pk =
                ((unsigned long long)__float_as_uint(zz) << 32) | (unsigned)f;
            atomicMin(&cells[Y * W_ + X], pk);   // fire-and-forget: no wait
        }
        xx += r64; yy += q64;
        if (xx >= wX) { xx -= wX; yy += 1; }
    }
}

// Decode winner, shade (same arithmetic as validated r3), composite in
// ts-sorted order. Latency-bound: 128 blocks x 128 threads spreads the
// ~2us-per-thread load chains over 2x more CUs than 64x256; the three pk
// loads are hoisted so all three chains issue their heads back-to-back.
__global__ __launch_bounds__(128) void shade_composite(
    const float4* __restrict__ faceA,
    const float4* __restrict__ faceB,
    const int*    __restrict__ faces,
    const float*  __restrict__ uv,
    const float*  __restrict__ tex,
    const float*  __restrict__ ts,
    const unsigned long long* __restrict__ packed,
    float* __restrict__ out)
{
#pragma clang fp contract(off)
    int pix = blockIdx.x * 128 + threadIdx.x;
    int y = pix >> 7;
    int x = pix & (W_ - 1);

    const double STEP = 2.0 / 127.0;
    float px = (float)(-1.0 + (double)x * STEP);
    float py = (float)( 1.0 - (double)y * STEP);

    const unsigned MISS_BITS = __float_as_uint(1e10f);

    unsigned long long pk0 = packed[0 * HW_ + pix];
    unsigned long long pk1 = packed[1 * HW_ + pix];
    unsigned long long pk2 = packed[2 * HW_ + pix];
    unsigned long long pks[B_] = {pk0, pk1, pk2};

    float rr[B_], gg[B_], bb_[B_], mm[B_];
    for (int b = 0; b < B_; ++b) {
        unsigned long long pk = pks[b];
        unsigned zbits = (unsigned)(pk >> 32);
        bool hard = zbits < MISS_BITS;
        float r = 0.0f, g = 0.0f, bl = 0.0f, m = 0.0f;
        if (hard) {
            m = 1.0f;
            int fi = (int)(unsigned)pk;   // face idx within batch
            float4 A = faceA[b * F_ + fi];
            float4 Bv = faceB[b * F_ + fi];
            float dx = px - Bv.x;
            float dy = py - Bv.y;
            float n0 = A.x*dx + A.y*dy;
            float n1 = A.z*dx + A.w*dy;
            float l0 = n0 / Bv.z;
            float l1 = n1 / Bv.z;
            float l2 = 1.0f - l0 - l1;

            int i0 = faces[fi*3+0];
            int i1 = faces[fi*3+1];
            int i2 = faces[fi*3+2];
            const float* uvb = uv + b * P_ * 2;
            float u0 = uvb[i0*2+0], v0 = uvb[i0*2+1];
            float u1 = uvb[i1*2+0], v1 = uvb[i1*2+1];
            float u2 = uvb[i2*2+0], v2 = uvb[i2*2+1];
            float tu = (l0*u0 + l1*u1) + l2*u2;
            float tv = (l0*v0 + l1*v1) + l2*v2;
            float uc = fminf(fmaxf(tu, 0.0f), 1.0f);
            float vc = fminf(fmaxf(tv, 0.0f), 1.0f);
            int txi = (int)rintf(uc * 511.0f);
            int tyi = (int)rintf((1.0f - vc) * 511.0f);
            const float* tb = tex + b * 3 * 512 * 512;
            r  = tb[(0*512 + tyi)*512 + txi];
            g  = tb[(1*512 + tyi)*512 + txi];
            bl = tb[(2*512 + tyi)*512 + txi];
        }
        rr[b] = r; gg[b] = g; bb_[b] = bl; mm[b] = m;
    }

    // stable sort descending by ts[:,2] (argsort(-ts[:,2]))
    float k0 = ts[0*3+2], k1 = ts[1*3+2], k2 = ts[2*3+2];
    int o0 = 0, o1 = 1, o2 = 2;
    if (k1 > k0) { int ti=o0; o0=o1; o1=ti; float tf=k0; k0=k1; k1=tf; }
    if (k2 > k1) { int ti=o1; o1=o2; o2=ti; float tf=k1; k1=k2; k2=tf; }
    if (k1 > k0) { int ti=o0; o0=o1; o1=ti; float tf=k0; k0=k1; k1=tf; }

    float sr = rr[o0], sg = gg[o0], sb = bb_[o0], sm = mm[o0];
    if (mm[o1] > 0.5f) { sr = rr[o1]; sg = gg[o1]; sb = bb_[o1]; sm = mm[o1]; }
    if (mm[o2] > 0.5f) { sr = rr[o2]; sg = gg[o2]; sb = bb_[o2]; sm = mm[o2]; }

    out[pix*3+0] = sr;
    out[pix*3+1] = sg;
    out[pix*3+2] = sb;
    out[OFF_PROB + pix] = sm;  // improb
    out[OFF_FG   + pix] = sm;  // fg
}

extern "C" void kernel_launch(void* const* d_in, const int* in_sizes, int n_in,
                              void* d_out, int out_size, void* d_ws, size_t ws_size,
                              hipStream_t stream) {
    const float* points = (const float*)d_in[0];
    const float* camrot = (const float*)d_in[1];
    const float* campos = (const float*)d_in[2];
    const float* proj   = (const float*)d_in[3];
    const float* uv     = (const float*)d_in[4];
    const float* tex    = (const float*)d_in[5];
    const float* ts     = (const float*)d_in[6];
    const int*   faces  = (const int*)d_in[7];
    float* out = (float*)d_out;

    char* ws = (char*)d_ws;
    float4* faceA = (float4*)(ws);
    float4* faceB = (float4*)(ws + 49152);
    unsigned long long* packed = (unsigned long long*)(ws + 98304);

    // init depth cells to u64-max (miss). Misses never write in fwd raster.
    hipMemsetAsync(packed, 0xFF, (size_t)B_ * HW_ * 8, stream);

    raster_fwd<<<dim3(B_*F_/4), dim3(256), 0, stream>>>(
        points, camrot, campos, proj, faces, faceA, faceB, packed,
        out + OFF_NORM);
    shade_composite<<<dim3(HW_/128), dim3(128), 0, stream>>>(
        faceA, faceB, faces, uv, tex, ts, packed, out);
}

// Round 9
// 88.508 us; speedup vs baseline: 1.1074x; 1.0035x over previous
//
#include <hip/hip_runtime.h>
#include <math.h>

#define B_ 3
#define P_ 768
#define F_ 1024
#define H_ 128
#define W_ 128
#define HW_ (H_*W_)
#define EPS_ 1e-8f

// Output layout (flat concat, floats):
//   imrender (1,128,128,3) : offset 0,      49152
//   improb   (128,128,1)   : offset 49152,  16384
//   normals  (3,1024,3)    : offset 65536,   9216
//   fg       (1,128,128,1) : offset 74752,  16384
#define OFF_PROB   49152
#define OFF_NORM   65536
#define OFF_FG     74752

// Workspace layout (bytes):
//   faceA:  B*F float4  (e0x,e0y,e1x,e1y)        @ 0       (49152 B)
//   faceB:  B*F float4  (cx,cy,denom,valid)      @ 49152   (49152 B)
//   faceC:  B*F float4  (u0,v0,u1,v1)            @ 98304   (49152 B)
//   faceD:  B*F float2  (u2,v2)                  @ 147456  (24576 B)
//   packed: B*HW u64    ((z_bits<<32)|faceidx)   @ 172032  (393216 B)
// NOTE: harness poisons the FULL 256 MiB d_ws to 0xAA every timed iter —
// ~41 us of measured time, untouchable. Fixed floor ~64 us incl. restores.
// memset of packed kept: correctness-call ws state is not guaranteed poisoned.

// Forward rasterizer (validated r6/r8): waves compute face setup in-register,
// lane 0 of sub-wave 0 writes normals + per-face shading data (incl. UVs so
// shade skips the faces->uv double indirection), lanes stripe the conservative
// pixel bbox and atomicMin packed (z_bits<<32)|idx. Positive-float bits are
// value-monotone, so u64-min == (min z, then min idx) == jnp.argmin
// first-occurrence tie-break — order-independent across waves.
// grid (768, 2): each face is split across 2 sub-waves (interleaved stripe)
// to halve the worst-case bbox tail (~56 -> ~28 iters).
// r7 LESSON: no load-filter before the atomic — result-unused atomicMin is
// fire-and-forget (no vmcnt wait); a filter load costs +8 us.
__global__ __launch_bounds__(256) void raster_fwd(
    const float* __restrict__ points,
    const float* __restrict__ camrot,
    const float* __restrict__ campos,
    const float* __restrict__ proj,
    const int*   __restrict__ faces,
    float4* __restrict__ faceA,
    float4* __restrict__ faceB,
    float4* __restrict__ faceC,
    float2* __restrict__ faceD,
    const float* __restrict__ uv,
    unsigned long long* __restrict__ packed,
    float*  __restrict__ normals_out)
{
#pragma clang fp contract(off)
    int wid  = blockIdx.x * 4 + (threadIdx.x >> 6);   // global face slot
    int sub  = blockIdx.y;                            // 0/1: bbox half
    int lane = threadIdx.x & 63;
    int b = wid / F_;
    int f = wid - b * F_;

    // ---- per-face setup (bit-identical to validated r3/r4, contract(off)) ----
    const float* R = camrot + b * 9;
    float cpx = campos[b*3+0], cpy = campos[b*3+1], cpz = campos[b*3+2];
    float pj0 = proj[0], pj1 = proj[1];

    int idx3[3];
    float pcx[3], pcy[3], pcz[3], sx[3], sy[3];
    for (int v = 0; v < 3; ++v) {
        int vi = faces[f*3 + v];
        idx3[v] = vi;
        const float* P = points + (b*P_ + vi) * 3;
        float vx = P[0] - cpx;
        float vy = P[1] - cpy;
        float vz = P[2] - cpz;
        float qx = (vx*R[0] + vy*R[1]) + vz*R[2];
        float qy = (vx*R[3] + vy*R[4]) + vz*R[5];
        float qz = (vx*R[6] + vy*R[7]) + vz*R[8];
        pcx[v] = qx; pcy[v] = qy; pcz[v] = qz;
        float dz = qz + EPS_;
        sx[v] = (qx * pj0) / dz;
        sy[v] = (qy * pj1) / dz;
    }

    float ax = sx[0], ay = sy[0];
    float bx = sx[1], by = sy[1];
    float cx = sx[2], cy = sy[2];

    float e0x = by - cy;
    float e0y = cx - bx;
    float e1x = cy - ay;
    float e1y = ax - cx;
    float d = e0x*(ax - cx) + e0y*(ay - cy);
    float denom = d + EPS_;
    bool valid = fabsf(d) > EPS_;
    float z0 = pcz[0], z1 = pcz[1], z2 = pcz[2];

    if (lane == 0 && sub == 0) {
        faceA[wid] = make_float4(e0x, e0y, e1x, e1y);
        faceB[wid] = make_float4(cx, cy, denom, valid ? 1.0f : 0.0f);
        const float* uvb = uv + b * P_ * 2;
        faceC[wid] = make_float4(uvb[idx3[0]*2+0], uvb[idx3[0]*2+1],
                                 uvb[idx3[1]*2+0], uvb[idx3[1]*2+1]);
        faceD[wid] = make_float2(uvb[idx3[2]*2+0], uvb[idx3[2]*2+1]);

        // normal: emulate XLA's LHS-fma contraction (validated bitwise, r3).
        float ux = pcx[1]-pcx[0], uy = pcy[1]-pcy[0], uz = pcz[1]-pcz[0];
        float wx = pcx[2]-pcx[0], wy = pcy[2]-pcy[0], wz = pcz[2]-pcz[0];
        float nx = fmaf(uy, wz, -(uz*wy));
        float ny = fmaf(uz, wx, -(ux*wz));
        float nz = fmaf(ux, wy, -(uy*wx));
        float nn = sqrtf((nx*nx + ny*ny) + nz*nz) + 1e-8f;
        normals_out[wid*3+0] = nx / nn;
        normals_out[wid*3+1] = ny / nn;
        normals_out[wid*3+2] = nz / nn;
    }

    if (!valid) return;   // inside==false for every pixel of this face

    // ---- conservative pixel-index bbox (1-px guard, validated r6) ----
    float gx0 = (ax + 1.0f) * 63.5f;
    float gx1 = (bx + 1.0f) * 63.5f;
    float gx2 = (cx + 1.0f) * 63.5f;
    float gy0 = (1.0f - ay) * 63.5f;
    float gy1 = (1.0f - by) * 63.5f;
    float gy2 = (1.0f - cy) * 63.5f;
    int xlo = max(0,   (int)ceilf (fminf(fminf(gx0,gx1),gx2) - 1.0f));
    int xhi = min(127, (int)floorf(fmaxf(fmaxf(gx0,gx1),gx2) + 1.0f));
    int ylo = max(0,   (int)ceilf (fminf(fminf(gy0,gy1),gy2) - 1.0f));
    int yhi = min(127, (int)floorf(fmaxf(fmaxf(gy0,gy1),gy2) + 1.0f));
    int wX = xhi - xlo + 1;
    int wY = yhi - ylo + 1;
    if (wX <= 0 || wY <= 0) return;
    int N = wX * wY;

    // interleaved stripe across the 2 sub-waves: i = sub*64+lane, step 128.
    int i0 = sub * 64 + lane;
    if (i0 >= N) return;
    int q = 128 / wX;
    int r = 128 - q * wX;
    int yy = i0 / wX;
    int xx = i0 - yy * wX;

    const double STEP = 2.0 / 127.0;
    unsigned long long* cells = packed + b * HW_;

    for (int i = i0; i < N; i += 128) {
        int X = xlo + xx;
        int Y = ylo + yy;
        float px = (float)(-1.0 + (double)X * STEP);
        float py = (float)( 1.0 - (double)Y * STEP);
        float dx = px - cx;
        float dy = py - cy;
        float n0 = e0x*dx + e0y*dy;
        float n1 = e1x*dx + e1y*dy;
        float l0 = n0 / denom;
        float l1 = n1 / denom;
        float l2 = 1.0f - l0 - l1;
        float zz = (l0*z0 + l1*z1) + l2*z2;
        if (l0 >= 0.0f && l1 >= 0.0f && l2 >= 0.0f && zz > EPS_) {
            unsigned long long pk =
                ((unsigned long long)__float_as_uint(zz) << 32) | (unsigned)f;
            atomicMin(&cells[Y * W_ + X], pk);   // fire-and-forget: no wait
        }
        xx += r; yy += q;
        if (xx >= wX) { xx -= wX; yy += 1; }
    }
}

// Decode winners, shade, composite. Staged + branchless: the 3 batches'
// dependency chains advance in lockstep (pk loads -> face-data loads ->
// compute -> tex loads), so load latency overlaps 3-wide. Non-hard lanes use
// fi=0 (always-valid), compute finite garbage, and multiply by mask 0.0f at
// the end — value-identical to the branched path (clamps eat NaN/inf before
// any index; AMD fminf/fmaxf return the non-NaN operand).
__global__ __launch_bounds__(128) void shade_composite(
    const float4* __restrict__ faceA,
    const float4* __restrict__ faceB,
    const float4* __restrict__ faceC,
    const float2* __restrict__ faceD,
    const float*  __restrict__ tex,
    const float*  __restrict__ ts,
    const unsigned long long* __restrict__ packed,
    float* __restrict__ out)
{
#pragma clang fp contract(off)
    int pix = blockIdx.x * 128 + threadIdx.x;
    int y = pix >> 7;
    int x = pix & (W_ - 1);

    const double STEP = 2.0 / 127.0;
    float px = (float)(-1.0 + (double)x * STEP);
    float py = (float)( 1.0 - (double)y * STEP);

    const unsigned MISS_BITS = __float_as_uint(1e10f);

    // stage 1: all pk loads
    unsigned long long pks[B_];
    for (int b = 0; b < B_; ++b) pks[b] = packed[b * HW_ + pix];

    // stage 2: all face-data loads (fi=0 fallback keeps indices valid)
    float m[B_]; int fi[B_];
    float4 A[B_], Bv[B_], Cv[B_]; float2 Dv[B_];
    for (int b = 0; b < B_; ++b) {
        bool hard = (unsigned)(pks[b] >> 32) < MISS_BITS;
        m[b]  = hard ? 1.0f : 0.0f;
        fi[b] = hard ? (int)(unsigned)pks[b] : 0;
        A[b]  = faceA[b * F_ + fi[b]];
        Bv[b] = faceB[b * F_ + fi[b]];
        Cv[b] = faceC[b * F_ + fi[b]];
        Dv[b] = faceD[b * F_ + fi[b]];
    }

    // stage 3: barycentrics + tex indices (same expressions as validated r3)
    int txi[B_], tyi[B_];
    for (int b = 0; b < B_; ++b) {
        float dx = px - Bv[b].x;
        float dy = py - Bv[b].y;
        float n0 = A[b].x*dx + A[b].y*dy;
        float n1 = A[b].z*dx + A[b].w*dy;
        float l0 = n0 / Bv[b].z;
        float l1 = n1 / Bv[b].z;
        float l2 = 1.0f - l0 - l1;
        float tu = (l0*Cv[b].x + l1*Cv[b].z) + l2*Dv[b].x;
        float tv = (l0*Cv[b].y + l1*Cv[b].w) + l2*Dv[b].y;
        float uc = fminf(fmaxf(tu, 0.0f), 1.0f);
        float vc = fminf(fmaxf(tv, 0.0f), 1.0f);
        txi[b] = (int)rintf(uc * 511.0f);
        tyi[b] = (int)rintf((1.0f - vc) * 511.0f);
    }

    // stage 4: all tex loads, then mask
    float rr[B_], gg[B_], bb_[B_];
    for (int b = 0; b < B_; ++b) {
        const float* tb = tex + b * 3 * 512 * 512;
        int o = tyi[b]*512 + txi[b];
        rr[b]  = tb[0*262144 + o] * m[b];
        gg[b]  = tb[1*262144 + o] * m[b];
        bb_[b] = tb[2*262144 + o] * m[b];
    }

    // stable sort descending by ts[:,2] (argsort(-ts[:,2]))
    float k0 = ts[0*3+2], k1 = ts[1*3+2], k2 = ts[2*3+2];
    int o0 = 0, o1 = 1, o2 = 2;
    if (k1 > k0) { int ti=o0; o0=o1; o1=ti; float tf=k0; k0=k1; k1=tf; }
    if (k2 > k1) { int ti=o1; o1=o2; o2=ti; float tf=k1; k1=k2; k2=tf; }
    if (k1 > k0) { int ti=o0; o0=o1; o1=ti; float tf=k0; k0=k1; k1=tf; }

    float sr = rr[o0], sg = gg[o0], sb = bb_[o0], sm = m[o0];
    if (m[o1] > 0.5f) { sr = rr[o1]; sg = gg[o1]; sb = bb_[o1]; sm = m[o1]; }
    if (m[o2] > 0.5f) { sr = rr[o2]; sg = gg[o2]; sb = bb_[o2]; sm = m[o2]; }

    out[pix*3+0] = sr;
    out[pix*3+1] = sg;
    out[pix*3+2] = sb;
    out[OFF_PROB + pix] = sm;  // improb
    out[OFF_FG   + pix] = sm;  // fg
}

extern "C" void kernel_launch(void* const* d_in, const int* in_sizes, int n_in,
                              void* d_out, int out_size, void* d_ws, size_t ws_size,
                              hipStream_t stream) {
    const float* points = (const float*)d_in[0];
    const float* camrot = (const float*)d_in[1];
    const float* campos = (const float*)d_in[2];
    const float* proj   = (const float*)d_in[3];
    const float* uv     = (const float*)d_in[4];
    const float* tex    = (const float*)d_in[5];
    const float* ts     = (const float*)d_in[6];
    const int*   faces  = (const int*)d_in[7];
    float* out = (float*)d_out;

    char* ws = (char*)d_ws;
    float4* faceA = (float4*)(ws);
    float4* faceB = (float4*)(ws + 49152);
    float4* faceC = (float4*)(ws + 98304);
    float2* faceD = (float2*)(ws + 147456);
    unsigned long long* packed = (unsigned long long*)(ws + 172032);

    // init depth cells to u64-max (miss). Misses never write in fwd raster.
    hipMemsetAsync(packed, 0xFF, (size_t)B_ * HW_ * 8, stream);

    raster_fwd<<<dim3(B_*F_/4, 2), dim3(256), 0, stream>>>(
        points, camrot, campos, proj, faces, faceA, faceB, faceC, faceD, uv,
        packed, out + OFF_NORM);
    shade_composite<<<dim3(HW_/128), dim3(128), 0, stream>>>(
        faceA, faceB, faceC, faceD, tex, ts, packed, out);
}